// Round 9
// baseline (265.020 us; speedup 1.0000x reference)
//
#include <hip/hip_runtime.h>

#define NN 50000
#define EE 400000
#define GG 500
#define F_IN 92
#define KP1 96      // F_IN padded to multiple of 32
#define D_H 256
#define D_EMB 128
#define NB_SCAN 196 // ceil(NN/256)
#define GEMM_G 256  // persistent GEMM blocks (1 per CU)

typedef __attribute__((ext_vector_type(8))) short short8_t;
typedef __attribute__((ext_vector_type(4))) float floatx4;
typedef unsigned short u16;
typedef unsigned int u32;

__device__ __forceinline__ float lrelu(float v) { return v > 0.f ? v : 0.01f * v; }
__device__ __forceinline__ u16 f2b(float v) {
    union { float f; u32 u; } x; x.f = v;
    u32 r = x.u + 0x7FFFu + ((x.u >> 16) & 1u);   // RNE
    return (u16)(r >> 16);
}
__device__ __forceinline__ float wave_allsum(float v) {
#pragma unroll
    for (int m = 1; m < 64; m <<= 1) v += __shfl_xor(v, m);
    return v;
}

// ---------------- scan1: block-local exclusive prefix of cnt (+ fused dinv) ---------
__global__ void scan1(const int* __restrict__ cnt, int* __restrict__ excl,
                      int* __restrict__ bsum, float* __restrict__ dinv, int n) {
    __shared__ int sm[256];
    int i = blockIdx.x * 256 + threadIdx.x;
    int v = (i < n) ? cnt[i] : 0;
    if (i < n) dinv[i] = rsqrtf((float)v + 1.0f);   // +1 self loop
    sm[threadIdx.x] = v;
    __syncthreads();
#pragma unroll
    for (int off = 1; off < 256; off <<= 1) {
        int t = (threadIdx.x >= off) ? sm[threadIdx.x - off] : 0;
        __syncthreads();
        sm[threadIdx.x] += t;
        __syncthreads();
    }
    if (i < n) excl[i] = sm[threadIdx.x] - v;
    if (threadIdx.x == 255) bsum[blockIdx.x] = sm[255];
}

// --------- scan2+scan3 in ONE kernel: each block reduces its own bsum prefix ---------
__global__ void scan23(int* __restrict__ rowptr, const int* __restrict__ bsum) {
    __shared__ int sm[256];
    int b = blockIdx.x;
    int v = ((int)threadIdx.x < b) ? bsum[threadIdx.x] : 0;   // NB_SCAN-1 < 256
    sm[threadIdx.x] = v;
    __syncthreads();
#pragma unroll
    for (int off = 128; off > 0; off >>= 1) {
        if ((int)threadIdx.x < off) sm[threadIdx.x] += sm[threadIdx.x + off];
        __syncthreads();
    }
    int base = sm[0];
    int i = b * 256 + threadIdx.x;
    if (i < NN) rowptr[i] += base;
    if (i == 0) rowptr[NN] = EE;
}

// ---------------- all three weight transpose-casts in one kernel ----------------
#define WN_ELEMS (D_H * KP1)      // 24576
#define W1_ELEMS (D_H * D_H)      // 65536
#define W2_ELEMS (D_EMB * D_H)    // 32768
__global__ void cast_all(const float* __restrict__ nfc_W, const float* __restrict__ gc1_W,
                         const float* __restrict__ gc2_W, u16* __restrict__ WtN,
                         u16* __restrict__ Wt1, u16* __restrict__ Wt2) {
    int i = blockIdx.x * blockDim.x + threadIdx.x;
    if (i < WN_ELEMS) {
        int n = i / KP1, k = i % KP1;
        WtN[i] = f2b(k < F_IN ? nfc_W[(long)k * D_H + n] : 0.f);
    } else if (i < WN_ELEMS + W1_ELEMS) {
        int j = i - WN_ELEMS;
        int n = j / D_H, k = j % D_H;
        Wt1[j] = f2b(gc1_W[(long)k * D_H + n]);
    } else if (i < WN_ELEMS + W1_ELEMS + W2_ELEMS) {
        int j = i - WN_ELEMS - W1_ELEMS;
        int n = j / D_H, k = j % D_H;
        Wt2[j] = f2b(gc2_W[(long)k * D_EMB + n]);
    }
}

// ---- persistent GEMM-1 (+fused degree count): B (256x96) staged ONCE, M-loop -------
// Each of 256 blocks stages B in fragment-order LDS once, then loops over 64-row
// M-tiles (782 jobs, ~3/block) with one-job-lookahead A double-buffer (fp32 loads,
// in-register bf16 pack). Barrier-free main loop. Blocks >= G1 run the degree count.
#define MBF ((NN + 63) / 64)   // 782
#define LOADAF(T0, T1, MB) do {                                                 \
    int _gmA = (MB) * 64 + wave * 16 + lm;                                      \
    const float* _Af = Af_ + (size_t)_gmA * F_IN;                               \
    _Pragma("unroll")                                                           \
    for (int _t = 0; _t < 3; ++_t) {                                            \
        int _c0 = _t * 32 + lk * 8;                                             \
        T0[_t] = make_float4(0.f, 0.f, 0.f, 0.f);                               \
        T1[_t] = make_float4(0.f, 0.f, 0.f, 0.f);                               \
        if (_gmA < NN) {                                                        \
            T0[_t] = *(const float4*)(_Af + _c0);                               \
            if (_c0 + 8 <= F_IN) T1[_t] = *(const float4*)(_Af + _c0 + 4);      \
        }                                                                       \
    } } while (0)
#define COMPSTF(T0, T1, MB) do {                                                \
    short8_t _af[3];                                                            \
    _Pragma("unroll")                                                           \
    for (int _t = 0; _t < 3; ++_t) {                                            \
        union { u32 u[4]; short8_t v; } _p;                                     \
        _p.u[0] = ((u32)f2b(T0[_t].y) << 16) | f2b(T0[_t].x);                   \
        _p.u[1] = ((u32)f2b(T0[_t].w) << 16) | f2b(T0[_t].z);                   \
        _p.u[2] = ((u32)f2b(T1[_t].y) << 16) | f2b(T1[_t].x);                   \
        _p.u[3] = ((u32)f2b(T1[_t].w) << 16) | f2b(T1[_t].z);                   \
        _af[_t] = _p.v;                                                         \
    }                                                                           \
    floatx4 _ac[16] = {};                                                       \
    _Pragma("unroll")                                                           \
    for (int _t = 0; _t < 3; ++_t) {                                            \
        const u16* _bp = &Bs[(_t * 64 + lk * 16 + lm) * 8];                     \
        _Pragma("unroll")                                                       \
        for (int _c = 0; _c < 16; ++_c) {                                       \
            short8_t _bf = *(const short8_t*)(_bp + _c * 3 * 512);              \
            _ac[_c] = __builtin_amdgcn_mfma_f32_16x16x32_bf16(_af[_t], _bf, _ac[_c], 0, 0, 0); \
        }                                                                       \
    }                                                                           \
    int _m0 = (MB) * 64 + wave * 16;                                            \
    _Pragma("unroll")                                                           \
    for (int _r = 0; _r < 4; ++_r) {                                            \
        int _gm = _m0 + lk * 4 + _r;                                            \
        if (_gm < NN) {                                                         \
            _Pragma("unroll")                                                   \
            for (int _c = 0; _c < 16; ++_c) {                                   \
                int _gn = _c * 16 + lm;                                         \
                out[(size_t)_gm * D_H + _gn] = f2b(lrelu(_ac[_c][_r] + bias[_gn])); \
            }                                                                   \
        }                                                                       \
    } } while (0)
__global__ __launch_bounds__(256, 1) void gemm_f32a(const float* __restrict__ Af_,
                                                    const u16* __restrict__ Wt,
                                                    const float* __restrict__ bias,
                                                    u16* __restrict__ out,
                                                    const int* __restrict__ dstE,
                                                    int* __restrict__ cnt,
                                                    int G1) {
    if ((int)blockIdx.x >= G1) {   // -------- fused count path --------
        int e = (blockIdx.x - G1) * 256 + threadIdx.x;
        if (e < EE) atomicAdd(&cnt[dstE[e]], 1);
        return;
    }
    __shared__ u16 Bs[D_H * KP1];   // 48KB fragment-ordered
    int tid = threadIdx.x;
    int wave = tid >> 6, lane = tid & 63;
    int lm = lane & 15, lk = lane >> 4;
    int bl = blockIdx.x;
    float4 xa0[3], xa1[3], ya0[3], ya1[3];
    LOADAF(xa0, xa1, bl);           // first job's A in flight under staging
    {
        int lmS = tid & 15, cS = tid >> 4;
        const u16* Wb = Wt + (size_t)(cS * 16 + lmS) * KP1;
#pragma unroll
        for (int it = 0; it < KP1 / 8; ++it) {            // 12
            uint4 v = *(const uint4*)(Wb + it * 8);
            int t = it >> 2, lk2 = it & 3;
            *(uint4*)&Bs[(((cS * 3 + t) * 64) + lk2 * 16 + lmS) * 8] = v;
        }
    }
    __syncthreads();
    int mb = bl;
    bool useX = true;
    while (mb < MBF) {
        int nmb = mb + GEMM_G;
        if (useX) {
            if (nmb < MBF) LOADAF(ya0, ya1, nmb);
            COMPSTF(xa0, xa1, mb);
        } else {
            if (nmb < MBF) LOADAF(xa0, xa1, nmb);
            COMPSTF(ya0, ya1, mb);
        }
        useX = !useX;
        mb = nmb;
    }
}

// ---- persistent GEMM-2/3 (+fused scatter): B half staged ONCE, barrier-free M-loop --
// NS col-splits of 128; G1/NS blocks per split; each block ~3 (conv1) / ~2 (conv2)
// 128-row M-tiles with one-job-lookahead A double-buffer. A rows are L3-resident
// (written by the previous stage). OOB tail rows read adjacent ws memory; never stored.
#define MBC ((NN + 127) / 128)  // 391
#define LOADA(D0, D1, MB) do {                                                  \
    const u16* _p0 = A + (size_t)((MB) * 128 + wave * 32 + lm) * D_H + lk * 8;  \
    const u16* _p1 = _p0 + (size_t)16 * D_H;                                    \
    _Pragma("unroll")                                                           \
    for (int _t = 0; _t < 8; ++_t) {                                            \
        D0[_t] = *(const short8_t*)(_p0 + _t * 32);                             \
        D1[_t] = *(const short8_t*)(_p1 + _t * 32);                             \
    } } while (0)
#define COMPST(A0, A1, MB) do {                                                 \
    floatx4 _ac0[8] = {}, _ac1[8] = {};                                         \
    _Pragma("unroll")                                                           \
    for (int _t = 0; _t < 8; ++_t) {                                            \
        const u16* _bp = &Bs[(_t * 64 + lk * 16 + lm) * 8];                     \
        _Pragma("unroll")                                                       \
        for (int _c = 0; _c < 8; ++_c) {                                        \
            short8_t _bf = *(const short8_t*)(_bp + _c * 8 * 512);              \
            _ac0[_c] = __builtin_amdgcn_mfma_f32_16x16x32_bf16(A0[_t], _bf, _ac0[_c], 0, 0, 0); \
            _ac1[_c] = __builtin_amdgcn_mfma_f32_16x16x32_bf16(A1[_t], _bf, _ac1[_c], 0, 0, 0); \
        }                                                                       \
    }                                                                           \
    int _r0 = (MB) * 128 + wave * 32;                                           \
    _Pragma("unroll")                                                           \
    for (int _r = 0; _r < 4; ++_r) {                                            \
        int _gm0 = _r0 + lk * 4 + _r, _gm1 = _gm0 + 16;                         \
        if (_gm0 < NN) {                                                        \
            float _rs = rscale[_gm0];                                           \
            _Pragma("unroll")                                                   \
            for (int _c = 0; _c < 8; ++_c)                                      \
                out[(size_t)_gm0 * ND + ns * 128 + _c * 16 + lm] = f2b(_ac0[_c][_r] * _rs); \
        }                                                                       \
        if (_gm1 < NN) {                                                        \
            float _rs = rscale[_gm1];                                           \
            _Pragma("unroll")                                                   \
            for (int _c = 0; _c < 8; ++_c)                                      \
                out[(size_t)_gm1 * ND + ns * 128 + _c * 16 + lm] = f2b(_ac1[_c][_r] * _rs); \
        }                                                                       \
    } } while (0)
template <int ND, bool SCAT>
__global__ __launch_bounds__(256, 1) void gemm_pers(const u16* __restrict__ A,
                                                    const u16* __restrict__ Wt,
                                                    const float* __restrict__ rscale,
                                                    u16* __restrict__ out,
                                                    const int* __restrict__ srcE,
                                                    const int* __restrict__ dstE,
                                                    const int* __restrict__ rowptr,
                                                    int* __restrict__ cursor,
                                                    int* __restrict__ esrc,
                                                    int G1) {
    constexpr int NS = ND / 128;    // col-splits (2 / 1)
    if constexpr (SCAT) {
        if ((int)blockIdx.x >= G1) {   // -------- fused scatter path --------
            int e = (blockIdx.x - G1) * 256 + threadIdx.x;
            if (e < EE) {
                int d = dstE[e];
                int p = rowptr[d] + atomicAdd(&cursor[d], 1);
                esrc[p] = srcE[e];
            }
            return;
        }
    }
    __shared__ u16 Bs[128 * D_H];   // 64KB fragment-ordered
    int half = G1 / NS;             // blocks per col-split
    int ns = (NS == 2 && (int)blockIdx.x >= half) ? 1 : 0;
    int bl = blockIdx.x - ns * half;
    int tid = threadIdx.x;
    int wave = tid >> 6, lane = tid & 63;
    int lm = lane & 15, lk = lane >> 4;
    short8_t xa0[8], xa1[8], ya0[8], ya1[8];
    LOADA(xa0, xa1, bl);            // first job's A in flight under staging
    {
        const u16* Wb = Wt + (size_t)ns * 128 * D_H;
#pragma unroll
        for (int it = 0; it < 16; ++it) {
            int idx = it * 256 + tid;
            int lmS = idx & 15;
            int k8 = (idx >> 4) & 31;
            int cS = idx >> 9;
            uint4 v = *(const uint4*)(Wb + (size_t)(cS * 16 + lmS) * D_H + k8 * 8);
            int t = k8 >> 2, lk2 = k8 & 3;
            *(uint4*)&Bs[(((cS * 8 + t) * 64) + lk2 * 16 + lmS) * 8] = v;
        }
    }
    __syncthreads();
    int mb = bl;
    bool useX = true;
    while (mb < MBC) {
        int nmb = mb + half;
        if (useX) {
            if (nmb < MBC) LOADA(ya0, ya1, nmb);
            COMPST(xa0, xa1, mb);
        } else {
            if (nmb < MBC) LOADA(xa0, xa1, nmb);
            COMPST(ya0, ya1, mb);
        }
        useX = !useX;
        mb = nmb;
    }
}

// ------- fused CSR gather + self-loop + LayerNorm + lrelu (+L2) (+pool): wave/node ---
// Wave-uniform row addresses (SGPR base), 8 rows in flight. POOL: the 4 waves' final
// rows are staged in LDS and run-flushed by batch id -> hg atomics.
template <int U>
__device__ __forceinline__ void loadrow(const u32* __restrict__ p, u32* r) {
    if constexpr (U == 2) { uint2 t = *(const uint2*)p; r[0] = t.x; r[1] = t.y; }
    else                  { r[0] = *p; }
}
template <int D, bool L2N, bool TOBF, bool POOL>
__global__ __launch_bounds__(256) void agg_ln(const u16* __restrict__ y,
                                              const int* __restrict__ rowptr,
                                              const int* __restrict__ esrc,
                                              const float* __restrict__ dinv,
                                              const float* __restrict__ bias,
                                              const float* __restrict__ gamma,
                                              const float* __restrict__ beta,
                                              u16* __restrict__ outb,
                                              float* __restrict__ outf,
                                              const int* __restrict__ batch,
                                              float* __restrict__ hg) {
    constexpr int V = D / 64;    // elems per lane (4 / 2)
    constexpr int U = V / 2;     // dwords per lane (2 / 1)
    constexpr int RW = D / 2;    // dwords per row
    int wave = threadIdx.x >> 6, lane = threadIdx.x & 63;
    int i = blockIdx.x * 4 + wave;
    if constexpr (!POOL) { if (i >= NN) return; }
    int beg = __builtin_amdgcn_readfirstlane(rowptr[i]);
    int end = __builtin_amdgcn_readfirstlane(rowptr[i + 1]);
    const u32* yu = (const u32*)y;
    const int lu = lane * U;
    float accL[U] = {}, accH[U] = {};
    u32 r[8][U];
    int k = beg;
    for (; k + 7 < end; k += 8) {            // 8 rows in flight (mean degree = 8)
#pragma unroll
        for (int q = 0; q < 8; ++q) loadrow<U>(yu + (size_t)esrc[k + q] * RW + lu, r[q]);
#pragma unroll
        for (int j = 0; j < U; ++j) {
            float sL = 0.f, sH = 0.f;
#pragma unroll
            for (int q = 0; q < 8; ++q) {
                sL += __uint_as_float(r[q][j] << 16);
                sH += __uint_as_float(r[q][j] & 0xFFFF0000u);
            }
            accL[j] += sL; accH[j] += sH;
        }
    }
    for (; k + 3 < end; k += 4) {
#pragma unroll
        for (int q = 0; q < 4; ++q) loadrow<U>(yu + (size_t)esrc[k + q] * RW + lu, r[q]);
#pragma unroll
        for (int j = 0; j < U; ++j) {
            accL[j] += (__uint_as_float(r[0][j] << 16) + __uint_as_float(r[1][j] << 16))
                     + (__uint_as_float(r[2][j] << 16) + __uint_as_float(r[3][j] << 16));
            accH[j] += (__uint_as_float(r[0][j] & 0xFFFF0000u) + __uint_as_float(r[1][j] & 0xFFFF0000u))
                     + (__uint_as_float(r[2][j] & 0xFFFF0000u) + __uint_as_float(r[3][j] & 0xFFFF0000u));
        }
    }
    for (; k < end; ++k) {
        loadrow<U>(yu + (size_t)esrc[k] * RW + lu, r[0]);
#pragma unroll
        for (int j = 0; j < U; ++j) {
            accL[j] += __uint_as_float(r[0][j] << 16);
            accH[j] += __uint_as_float(r[0][j] & 0xFFFF0000u);
        }
    }
    // self loop
    loadrow<U>(yu + (size_t)i * RW + lu, r[0]);
#pragma unroll
    for (int j = 0; j < U; ++j) {
        accL[j] += __uint_as_float(r[0][j] << 16);
        accH[j] += __uint_as_float(r[0][j] & 0xFFFF0000u);
    }
    float di = dinv[i];
    float xv[V], lsum = 0.f;
#pragma unroll
    for (int j = 0; j < U; ++j) {
        xv[2 * j]     = accL[j] * di + bias[lane * V + 2 * j];
        xv[2 * j + 1] = accH[j] * di + bias[lane * V + 2 * j + 1];
    }
#pragma unroll
    for (int v = 0; v < V; ++v) lsum += xv[v];
    float mu = wave_allsum(lsum) * (1.0f / D);
    float l2 = 0.f;
#pragma unroll
    for (int v = 0; v < V; ++v) { xv[v] -= mu; l2 += xv[v] * xv[v]; }
    float rstd = rsqrtf(wave_allsum(l2) * (1.0f / D) + 1e-5f);
    float yv[V], ss = 0.f;
#pragma unroll
    for (int v = 0; v < V; ++v) {
        float t = xv[v] * rstd * gamma[lane * V + v] + beta[lane * V + v];
        t = lrelu(t);
        yv[v] = t; ss += t * t;
    }
    if constexpr (L2N) {
        float inv = 1.0f / fmaxf(sqrtf(wave_allsum(ss)), 1e-12f);
#pragma unroll
        for (int v = 0; v < V; ++v) yv[v] *= inv;
    }
    if constexpr (TOBF) {
        if constexpr (V == 4) {
            *(ushort4*)(outb + (size_t)i * D + lane * V) =
                make_ushort4(f2b(yv[0]), f2b(yv[1]), f2b(yv[2]), f2b(yv[3]));
        } else {
            *(ushort2*)(outb + (size_t)i * D + lane * V) = make_ushort2(f2b(yv[0]), f2b(yv[1]));
        }
    } else {
        if constexpr (V == 2) {
            *(float2*)(outf + (size_t)i * D + lane * V) = make_float2(yv[0], yv[1]);
        } else {
            *(float4*)(outf + (size_t)i * D + lane * V) = make_float4(yv[0], yv[1], yv[2], yv[3]);
        }
    }
    if constexpr (POOL) {   // D == D_EMB, V == 2: block-level run-flush pooling
        __shared__ float psm[4][D_EMB];
        __shared__ int pb[4];
        psm[wave][lane * 2]     = yv[0];
        psm[wave][lane * 2 + 1] = yv[1];
        if (lane == 0) pb[wave] = batch[i];
        __syncthreads();
        int tid = threadIdx.x;
        if (tid < D_EMB) {
            float acc = psm[0][tid];
            int cur = pb[0];
#pragma unroll
            for (int w = 1; w < 4; ++w) {
                if (pb[w] != cur) {
                    atomicAdd(&hg[(size_t)cur * D_EMB + tid], acc);
                    acc = 0.f; cur = pb[w];
                }
                acc += psm[w][tid];
            }
            atomicAdd(&hg[(size_t)cur * D_EMB + tid], acc);
        }
    }
}

// ---------- head MLP: one block (64 threads) per graph on pooled hg ----------
__global__ __launch_bounds__(64) void head_kernel(const float* __restrict__ hg,
                                                  const float* __restrict__ fc1W,
                                                  const float* __restrict__ fc1b,
                                                  const float* __restrict__ fc2W,
                                                  const float* __restrict__ fc2b,
                                                  float* __restrict__ out) {
    int g = blockIdx.x;
    int j = threadIdx.x;  // 0..63
    float h = fc1b[j];
#pragma unroll 8
    for (int k = 0; k < D_EMB; ++k) h += hg[(size_t)g * D_EMB + k] * fc1W[k * 64 + j];
    h = lrelu(h) * fc2W[j];
#pragma unroll
    for (int m = 1; m < 64; m <<= 1) h += __shfl_xor(h, m);
    if (j == 0) out[g] = h + fc2b[0];
}

static inline size_t align256(size_t x) { return (x + 255) & ~(size_t)255; }

extern "C" void kernel_launch(void* const* d_in, const int* in_sizes, int n_in,
                              void* d_out, int out_size, void* d_ws, size_t ws_size,
                              hipStream_t stream) {
    const float* x     = (const float*)d_in[0];
    const int*   ei    = (const int*)d_in[1];
    const int*   batch = (const int*)d_in[2];
    const float* nfc_W = (const float*)d_in[3];
    const float* nfc_b = (const float*)d_in[4];
    const float* gn1_g = (const float*)d_in[5];
    const float* gn1_b = (const float*)d_in[6];
    const float* gc1_W = (const float*)d_in[7];
    const float* gc1_b = (const float*)d_in[8];
    const float* gn2_g = (const float*)d_in[9];
    const float* gn2_b = (const float*)d_in[10];
    const float* gc2_W = (const float*)d_in[11];
    const float* gc2_b = (const float*)d_in[12];
    const float* fc1_W = (const float*)d_in[13];
    const float* fc1_b = (const float*)d_in[14];
    const float* fc2_W = (const float*)d_in[15];
    const float* fc2_b = (const float*)d_in[16];

    char* ws = (char*)d_ws;
    size_t off = 0;
    // cnt + cursor + hg contiguous -> single memset
    int*   cnt    = (int*)(ws + off);   off += (size_t)NN * 4;
    int*   cursor = (int*)(ws + off);   off += (size_t)NN * 4;
    float* hg     = (float*)(ws + off); off += align256((size_t)GG * D_EMB * 4);
    float* dinv   = (float*)(ws + off); off += align256((size_t)NN * 4);
    int*   rowptr = (int*)(ws + off);   off += align256((size_t)(NN + 1) * 4);
    int*   bsum   = (int*)(ws + off);   off += align256((size_t)256 * 4);
    int*   esrc   = (int*)(ws + off);   off += align256((size_t)EE * 4);
    u16*   WtN    = (u16*)(ws + off);   off += align256((size_t)D_H * KP1 * 2);
    u16*   Wt1    = (u16*)(ws + off);   off += align256((size_t)D_H * D_H * 2);
    u16*   Wt2    = (u16*)(ws + off);   off += align256((size_t)D_EMB * D_H * 2);
    u16*   ha1b   = (u16*)(ws + off);   off += align256((size_t)NN * D_H * 2);
    u16*   y1b    = (u16*)(ws + off);   off += align256((size_t)NN * D_H * 2);
    u16*   ha2b   = (u16*)(ws + off);   off += align256((size_t)NN * D_H * 2);
    u16*   y2b    = (u16*)(ws + off);   off += align256((size_t)NN * D_EMB * 2);

    const int* src = ei;
    const int* dst = ei + EE;
    float* out_scores = (float*)d_out;
    float* out_ha     = (float*)d_out + GG;

    const int EB = (EE + 255) / 256;   // edge blocks riding inside fused dispatches
    const size_t zbytes = (size_t)NN * 8 + (size_t)GG * D_EMB * 4;  // cnt+cursor+hg

    // 1) one memset; weight casts (needed before GEMM-1)
    hipMemsetAsync(cnt, 0, zbytes, stream);
    cast_all<<<(WN_ELEMS + W1_ELEMS + W2_ELEMS + 255) / 256, 256, 0, stream>>>(
        nfc_W, gc1_W, gc2_W, WtN, Wt1, Wt2);

    // 2) persistent GEMM-1 (ha1 = lrelu(x @ nfc_W + b)) — with fused degree count
    gemm_f32a<<<GEMM_G + EB, 256, 0, stream>>>(x, WtN, nfc_b, ha1b, dst, cnt, GEMM_G);

    // 3) scan: wide scan1 then merged scan2+scan3
    scan1<<<NB_SCAN, 256, 0, stream>>>(cnt, rowptr, bsum, dinv, NN);
    scan23<<<NB_SCAN, 256, 0, stream>>>(rowptr, bsum);

    // 4) persistent conv1 GEMM (2 col-splits, 128 blocks each) + fused scatter
    gemm_pers<D_H, true><<<GEMM_G + EB, 256, 0, stream>>>(
        ha1b, Wt1, dinv, y1b, src, dst, rowptr, cursor, esrc, GEMM_G);
    agg_ln<D_H, false, true, false><<<NN / 4, 256, 0, stream>>>(
        y1b, rowptr, esrc, dinv, gc1_b, gn1_g, gn1_b, ha2b, nullptr, nullptr, nullptr);

    // 5) persistent conv2 GEMM (1 col-split); fused agg+LN+L2+pool -> out_ha + hg
    gemm_pers<D_EMB, false><<<GEMM_G, 256, 0, stream>>>(
        ha2b, Wt2, dinv, y2b, nullptr, nullptr, nullptr, nullptr, nullptr, GEMM_G);
    agg_ln<D_EMB, true, false, true><<<NN / 4, 256, 0, stream>>>(
        y2b, rowptr, esrc, dinv, gc2_b, gn2_g, gn2_b, nullptr, out_ha, batch, hg);

    // 6) tiny head
    head_kernel<<<GG, 64, 0, stream>>>(hg, fc1_W, fc1_b, fc2_W, fc2_b, out_scores);
}

// Round 10
// 250.827 us; speedup vs baseline: 1.0566x; 1.0566x over previous
//
#include <hip/hip_runtime.h>

#define NN 50000
#define EE 400000
#define GG 500
#define F_IN 92
#define KP1 96      // F_IN padded to multiple of 32
#define D_H 256
#define D_EMB 128
#define NB_SCAN 196 // ceil(NN/256)

typedef __attribute__((ext_vector_type(8))) short short8_t;
typedef __attribute__((ext_vector_type(4))) float floatx4;
typedef unsigned short u16;
typedef unsigned int u32;

__device__ __forceinline__ float lrelu(float v) { return v > 0.f ? v : 0.01f * v; }
__device__ __forceinline__ u16 f2b(float v) {
    union { float f; u32 u; } x; x.f = v;
    u32 r = x.u + 0x7FFFu + ((x.u >> 16) & 1u);   // RNE
    return (u16)(r >> 16);
}
__device__ __forceinline__ float wave_allsum(float v) {
#pragma unroll
    for (int m = 1; m < 64; m <<= 1) v += __shfl_xor(v, m);
    return v;
}
// direct global->LDS DMA, 16 B per lane; LDS dest = wave-uniform base + lane*16
__device__ __forceinline__ void glds16(const void* g, void* l) {
    __builtin_amdgcn_global_load_lds(
        (const __attribute__((address_space(1))) void*)g,
        (__attribute__((address_space(3))) void*)l, 16, 0, 0);
}

// ---------------- scan1: block-local exclusive prefix of cnt (+ fused dinv) ---------
__global__ void scan1(const int* __restrict__ cnt, int* __restrict__ excl,
                      int* __restrict__ bsum, float* __restrict__ dinv, int n) {
    __shared__ int sm[256];
    int i = blockIdx.x * 256 + threadIdx.x;
    int v = (i < n) ? cnt[i] : 0;
    if (i < n) dinv[i] = rsqrtf((float)v + 1.0f);   // +1 self loop
    sm[threadIdx.x] = v;
    __syncthreads();
#pragma unroll
    for (int off = 1; off < 256; off <<= 1) {
        int t = (threadIdx.x >= off) ? sm[threadIdx.x - off] : 0;
        __syncthreads();
        sm[threadIdx.x] += t;
        __syncthreads();
    }
    if (i < n) excl[i] = sm[threadIdx.x] - v;
    if (threadIdx.x == 255) bsum[blockIdx.x] = sm[255];
}

// --------- scan2+scan3 in ONE kernel: each block reduces its own bsum prefix ---------
__global__ void scan23(int* __restrict__ rowptr, const int* __restrict__ bsum) {
    __shared__ int sm[256];
    int b = blockIdx.x;
    int v = ((int)threadIdx.x < b) ? bsum[threadIdx.x] : 0;   // NB_SCAN-1 < 256
    sm[threadIdx.x] = v;
    __syncthreads();
#pragma unroll
    for (int off = 128; off > 0; off >>= 1) {
        if ((int)threadIdx.x < off) sm[threadIdx.x] += sm[threadIdx.x + off];
        __syncthreads();
    }
    int base = sm[0];
    int i = b * 256 + threadIdx.x;
    if (i < NN) rowptr[i] += base;
    if (i == 0) rowptr[NN] = EE;
}

// ---------------- all three weight transpose-casts in one kernel ----------------
#define WN_ELEMS (D_H * KP1)      // 24576
#define W1_ELEMS (D_H * D_H)      // 65536
#define W2_ELEMS (D_EMB * D_H)    // 32768
__global__ void cast_all(const float* __restrict__ nfc_W, const float* __restrict__ gc1_W,
                         const float* __restrict__ gc2_W, u16* __restrict__ WtN,
                         u16* __restrict__ Wt1, u16* __restrict__ Wt2) {
    int i = blockIdx.x * blockDim.x + threadIdx.x;
    if (i < WN_ELEMS) {
        int n = i / KP1, k = i % KP1;
        WtN[i] = f2b(k < F_IN ? nfc_W[(long)k * D_H + n] : 0.f);
    } else if (i < WN_ELEMS + W1_ELEMS) {
        int j = i - WN_ELEMS;
        int n = j / D_H, k = j % D_H;
        Wt1[j] = f2b(gc1_W[(long)k * D_H + n]);
    } else if (i < WN_ELEMS + W1_ELEMS + W2_ELEMS) {
        int j = i - WN_ELEMS - W1_ELEMS;
        int n = j / D_H, k = j % D_H;
        Wt2[j] = f2b(gc2_W[(long)k * D_EMB + n]);
    }
}

// ------------- GEMM-1 (+fused degree count): fp32 A, full-N 128x256 tile -------------
// Blocks >= MBLK run the edge-degree count (independent work hidden under the GEMM).
__global__ __launch_bounds__(256) void gemm_f32a(const float* __restrict__ Af_,
                                                 const u16* __restrict__ Wt,
                                                 const float* __restrict__ bias,
                                                 u16* __restrict__ out,
                                                 const int* __restrict__ dstE,
                                                 int* __restrict__ cnt,
                                                 int MBLK) {
    if ((int)blockIdx.x >= MBLK) {   // -------- fused count path --------
        int e = (blockIdx.x - MBLK) * 256 + threadIdx.x;
        if (e < EE) atomicAdd(&cnt[dstE[e]], 1);
        return;
    }
    __shared__ u16 As[128][40];   // padded: manual uint4 writes
    __shared__ u16 Bs[256][32];   // glds-staged, unpadded (lane*16B linear)
    int tid = threadIdx.x;
    int wave = tid >> 6, lane = tid & 63;
    int lm = lane & 15, lk = lane >> 4;
    int m0 = blockIdx.x * 128;
    int rowA = tid >> 1, skA = (tid & 1) * 16;
    int lr = lane >> 2, lc = (lane & 3) * 8;
    int gmA = m0 + rowA;
    const float* Af = Af_ + (size_t)gmA * F_IN;
    const u16* Bp[4];
#pragma unroll
    for (int ch = 0; ch < 4; ++ch)
        Bp[ch] = Wt + (size_t)(wave * 64 + ch * 16 + lr) * KP1 + lc;
    floatx4 acc[2][16] = {};
    for (int k0 = 0; k0 < KP1; k0 += 32) {
        float f[16];
#pragma unroll
        for (int q = 0; q < 4; ++q) {
            int col = k0 + skA + 4 * q;
            float4 t = make_float4(0.f, 0.f, 0.f, 0.f);
            if (gmA < NN && col < F_IN) t = *(const float4*)(Af + col);  // F_IN%4==0
            f[4 * q] = t.x; f[4 * q + 1] = t.y; f[4 * q + 2] = t.z; f[4 * q + 3] = t.w;
        }
        u32 pk[8];
#pragma unroll
        for (int t2 = 0; t2 < 8; ++t2)
            pk[t2] = ((u32)f2b(f[2 * t2 + 1]) << 16) | f2b(f[2 * t2]);
        __syncthreads();                   // prior iter's LDS reads complete
        *(uint4*)&As[rowA][skA] = make_uint4(pk[0], pk[1], pk[2], pk[3]);
        *(uint4*)&As[rowA][skA + 8] = make_uint4(pk[4], pk[5], pk[6], pk[7]);
#pragma unroll
        for (int ch = 0; ch < 4; ++ch)
            glds16(Bp[ch] + k0, &Bs[wave * 64 + ch * 16][0]);
        __syncthreads();                   // drains vmcnt+lgkmcnt: tiles landed
        short8_t af0 = *(const short8_t*)&As[wave * 32 + lm][lk * 8];
        short8_t af1 = *(const short8_t*)&As[wave * 32 + 16 + lm][lk * 8];
#pragma unroll
        for (int c = 0; c < 16; ++c) {
            short8_t bf = *(const short8_t*)&Bs[c * 16 + lm][lk * 8];
            acc[0][c] = __builtin_amdgcn_mfma_f32_16x16x32_bf16(af0, bf, acc[0][c], 0, 0, 0);
            acc[1][c] = __builtin_amdgcn_mfma_f32_16x16x32_bf16(af1, bf, acc[1][c], 0, 0, 0);
        }
    }
#pragma unroll
    for (int h = 0; h < 2; ++h) {
#pragma unroll
        for (int r = 0; r < 4; ++r) {
            int gm = m0 + wave * 32 + h * 16 + lk * 4 + r;
            if (gm >= NN) continue;
#pragma unroll
            for (int c = 0; c < 16; ++c) {
                int gn = c * 16 + lm;
                float v = acc[h][c][r] + bias[gn];
                out[(size_t)gm * D_H + gn] = f2b(lrelu(v));
            }
        }
    }
}

// ------- GEMM-2/3 (+optional fused CSR scatter): 3-buffer LDS, COUNTED vmcnt ---------
// T4 pattern: per K-step only stage(t) must be complete; stage(t+1)'s NLD loads stay in
// flight across the barrier -> s_waitcnt vmcnt(NLD), never 0 until the last step.
// Stage(t+2) is issued AFTER the barrier: a fast wave cannot rewrite buf[t%3] until it
// passes barrier t+1, which requires all waves done reading buf[t%3]. 3 bufs = safe.
// OOB tail rows read into the adjacent ws buffer (valid memory); never stored.
template <int ND, bool SCAT>
__global__ __launch_bounds__(256) void gemm_glds(const u16* __restrict__ A,
                                                 const u16* __restrict__ Wt,
                                                 const float* __restrict__ rscale,
                                                 u16* __restrict__ out,
                                                 const int* __restrict__ srcE,
                                                 const int* __restrict__ dstE,
                                                 const int* __restrict__ rowptr,
                                                 int* __restrict__ cursor,
                                                 int* __restrict__ esrc,
                                                 int MBLK) {
    if constexpr (SCAT) {
        if ((int)blockIdx.x >= MBLK) {   // -------- fused scatter path --------
            int e = (blockIdx.x - MBLK) * 256 + threadIdx.x;
            if (e < EE) {
                int d = dstE[e];
                int p = rowptr[d] + atomicAdd(&cursor[d], 1);
                esrc[p] = srcE[e];
            }
            return;
        }
    }
    constexpr int NC  = ND / 16;    // MFMA col-fragments (16 / 8)
    constexpr int BCH = ND / 64;    // B glds chunks per wave (4 / 2)
    constexpr int NLD = 2 + BCH;    // glds per wave per stage (6 / 4)
    __shared__ u16 As[3][128][32];  // 24KB
    __shared__ u16 Bs[3][ND][32];   // 48KB / 24KB  -> 72KB (2 blk/CU) / 48KB (3 blk/CU)
    int tid = threadIdx.x;
    int wave = tid >> 6, lane = tid & 63;
    int lm = lane & 15, lk = lane >> 4;
    int m0 = blockIdx.x * 128;
    int lr = lane >> 2;            // 0..15: row within a 16-row chunk
    int lc = (lane & 3) * 8;       // u16 col offset (16 B granules)
    const int Ka = D_H;
    const u16* ApA = A + (size_t)(m0 + wave * 32 + lr) * Ka + lc;
    const u16* ApB = A + (size_t)(m0 + wave * 32 + 16 + lr) * Ka + lc;
    const u16* Bp[BCH];
#pragma unroll
    for (int ch = 0; ch < BCH; ++ch)
        Bp[ch] = Wt + (size_t)(wave * (ND / 4) + ch * 16 + lr) * Ka + lc;

    auto stage = [&](int b, int k0) {
        glds16(ApA + k0, &As[b][wave * 32][0]);
        glds16(ApB + k0, &As[b][wave * 32 + 16][0]);
#pragma unroll
        for (int ch = 0; ch < BCH; ++ch)
            glds16(Bp[ch] + k0, &Bs[b][wave * (ND / 4) + ch * 16][0]);
    };

    floatx4 acc[2][NC] = {};
    constexpr int nk = D_H / 32;    // 8
    stage(0, 0);                     // prologue: 2 stages in flight
    stage(1, 32);
#pragma unroll
    for (int t = 0; t < nk; ++t) {
        // stage(t) must be complete; stage(t+1) (NLD loads) may remain outstanding
        if (t + 1 < nk) {
            asm volatile("s_waitcnt vmcnt(%0)" :: "n"(NLD) : "memory");
        } else {
            asm volatile("s_waitcnt vmcnt(0)" ::: "memory");
        }
        __builtin_amdgcn_s_barrier();
        __builtin_amdgcn_sched_barrier(0);
        if (t + 2 < nk) stage((t + 2) % 3, (t + 2) * 32);   // post-barrier: race-free
        int cur = t % 3;
        short8_t af0 = *(const short8_t*)&As[cur][wave * 32 + lm][lk * 8];
        short8_t af1 = *(const short8_t*)&As[cur][wave * 32 + 16 + lm][lk * 8];
#pragma unroll
        for (int c = 0; c < NC; ++c) {
            short8_t bf = *(const short8_t*)&Bs[cur][c * 16 + lm][lk * 8];
            acc[0][c] = __builtin_amdgcn_mfma_f32_16x16x32_bf16(af0, bf, acc[0][c], 0, 0, 0);
            acc[1][c] = __builtin_amdgcn_mfma_f32_16x16x32_bf16(af1, bf, acc[1][c], 0, 0, 0);
        }
        __builtin_amdgcn_sched_barrier(0);   // keep this step's ds_reads/MFMAs in place
    }
#pragma unroll
    for (int h = 0; h < 2; ++h) {
#pragma unroll
        for (int r = 0; r < 4; ++r) {
            int gm = m0 + wave * 32 + h * 16 + lk * 4 + r;
            if (gm >= NN) continue;
            float rs = rscale[gm];
#pragma unroll
            for (int c = 0; c < NC; ++c) {
                int gn = c * 16 + lm;
                out[(size_t)gm * ND + gn] = f2b(acc[h][c][r] * rs);
            }
        }
    }
}

// ------- fused CSR gather + self-loop + LayerNorm + lrelu (+L2) (+pool): wave/node ---
// Wave-uniform row addresses (SGPR base), 8 rows in flight. POOL: the 4 waves' final
// rows are staged in LDS and run-flushed by batch id -> hg atomics.
template <int U>
__device__ __forceinline__ void loadrow(const u32* __restrict__ p, u32* r) {
    if constexpr (U == 2) { uint2 t = *(const uint2*)p; r[0] = t.x; r[1] = t.y; }
    else                  { r[0] = *p; }
}
template <int D, bool L2N, bool TOBF, bool POOL>
__global__ __launch_bounds__(256) void agg_ln(const u16* __restrict__ y,
                                              const int* __restrict__ rowptr,
                                              const int* __restrict__ esrc,
                                              const float* __restrict__ dinv,
                                              const float* __restrict__ bias,
                                              const float* __restrict__ gamma,
                                              const float* __restrict__ beta,
                                              u16* __restrict__ outb,
                                              float* __restrict__ outf,
                                              const int* __restrict__ batch,
                                              float* __restrict__ hg) {
    constexpr int V = D / 64;    // elems per lane (4 / 2)
    constexpr int U = V / 2;     // dwords per lane (2 / 1)
    constexpr int RW = D / 2;    // dwords per row
    int wave = threadIdx.x >> 6, lane = threadIdx.x & 63;
    int i = blockIdx.x * 4 + wave;
    if constexpr (!POOL) { if (i >= NN) return; }
    int beg = __builtin_amdgcn_readfirstlane(rowptr[i]);
    int end = __builtin_amdgcn_readfirstlane(rowptr[i + 1]);
    const u32* yu = (const u32*)y;
    const int lu = lane * U;
    float accL[U] = {}, accH[U] = {};
    u32 r[8][U];
    int k = beg;
    for (; k + 7 < end; k += 8) {            // 8 rows in flight (mean degree = 8)
#pragma unroll
        for (int q = 0; q < 8; ++q) loadrow<U>(yu + (size_t)esrc[k + q] * RW + lu, r[q]);
#pragma unroll
        for (int j = 0; j < U; ++j) {
            float sL = 0.f, sH = 0.f;
#pragma unroll
            for (int q = 0; q < 8; ++q) {
                sL += __uint_as_float(r[q][j] << 16);
                sH += __uint_as_float(r[q][j] & 0xFFFF0000u);
            }
            accL[j] += sL; accH[j] += sH;
        }
    }
    for (; k + 3 < end; k += 4) {
#pragma unroll
        for (int q = 0; q < 4; ++q) loadrow<U>(yu + (size_t)esrc[k + q] * RW + lu, r[q]);
#pragma unroll
        for (int j = 0; j < U; ++j) {
            accL[j] += (__uint_as_float(r[0][j] << 16) + __uint_as_float(r[1][j] << 16))
                     + (__uint_as_float(r[2][j] << 16) + __uint_as_float(r[3][j] << 16));
            accH[j] += (__uint_as_float(r[0][j] & 0xFFFF0000u) + __uint_as_float(r[1][j] & 0xFFFF0000u))
                     + (__uint_as_float(r[2][j] & 0xFFFF0000u) + __uint_as_float(r[3][j] & 0xFFFF0000u));
        }
    }
    for (; k < end; ++k) {
        loadrow<U>(yu + (size_t)esrc[k] * RW + lu, r[0]);
#pragma unroll
        for (int j = 0; j < U; ++j) {
            accL[j] += __uint_as_float(r[0][j] << 16);
            accH[j] += __uint_as_float(r[0][j] & 0xFFFF0000u);
        }
    }
    // self loop
    loadrow<U>(yu + (size_t)i * RW + lu, r[0]);
#pragma unroll
    for (int j = 0; j < U; ++j) {
        accL[j] += __uint_as_float(r[0][j] << 16);
        accH[j] += __uint_as_float(r[0][j] & 0xFFFF0000u);
    }
    float di = dinv[i];
    float xv[V], lsum = 0.f;
#pragma unroll
    for (int j = 0; j < U; ++j) {
        xv[2 * j]     = accL[j] * di + bias[lane * V + 2 * j];
        xv[2 * j + 1] = accH[j] * di + bias[lane * V + 2 * j + 1];
    }
#pragma unroll
    for (int v = 0; v < V; ++v) lsum += xv[v];
    float mu = wave_allsum(lsum) * (1.0f / D);
    float l2 = 0.f;
#pragma unroll
    for (int v = 0; v < V; ++v) { xv[v] -= mu; l2 += xv[v] * xv[v]; }
    float rstd = rsqrtf(wave_allsum(l2) * (1.0f / D) + 1e-5f);
    float yv[V], ss = 0.f;
#pragma unroll
    for (int v = 0; v < V; ++v) {
        float t = xv[v] * rstd * gamma[lane * V + v] + beta[lane * V + v];
        t = lrelu(t);
        yv[v] = t; ss += t * t;
    }
    if constexpr (L2N) {
        float inv = 1.0f / fmaxf(sqrtf(wave_allsum(ss)), 1e-12f);
#pragma unroll
        for (int v = 0; v < V; ++v) yv[v] *= inv;
    }
    if constexpr (TOBF) {
        if constexpr (V == 4) {
            *(ushort4*)(outb + (size_t)i * D + lane * V) =
                make_ushort4(f2b(yv[0]), f2b(yv[1]), f2b(yv[2]), f2b(yv[3]));
        } else {
            *(ushort2*)(outb + (size_t)i * D + lane * V) = make_ushort2(f2b(yv[0]), f2b(yv[1]));
        }
    } else {
        if constexpr (V == 2) {
            *(float2*)(outf + (size_t)i * D + lane * V) = make_float2(yv[0], yv[1]);
        } else {
            *(float4*)(outf + (size_t)i * D + lane * V) = make_float4(yv[0], yv[1], yv[2], yv[3]);
        }
    }
    if constexpr (POOL) {   // D == D_EMB, V == 2: block-level run-flush pooling
        __shared__ float psm[4][D_EMB];
        __shared__ int pb[4];
        psm[wave][lane * 2]     = yv[0];
        psm[wave][lane * 2 + 1] = yv[1];
        if (lane == 0) pb[wave] = batch[i];
        __syncthreads();
        int tid = threadIdx.x;
        if (tid < D_EMB) {
            float acc = psm[0][tid];
            int cur = pb[0];
#pragma unroll
            for (int w = 1; w < 4; ++w) {
                if (pb[w] != cur) {
                    atomicAdd(&hg[(size_t)cur * D_EMB + tid], acc);
                    acc = 0.f; cur = pb[w];
                }
                acc += psm[w][tid];
            }
            atomicAdd(&hg[(size_t)cur * D_EMB + tid], acc);
        }
    }
}

// ---------- head MLP: one block (64 threads) per graph on pooled hg ----------
__global__ __launch_bounds__(64) void head_kernel(const float* __restrict__ hg,
                                                  const float* __restrict__ fc1W,
                                                  const float* __restrict__ fc1b,
                                                  const float* __restrict__ fc2W,
                                                  const float* __restrict__ fc2b,
                                                  float* __restrict__ out) {
    int g = blockIdx.x;
    int j = threadIdx.x;  // 0..63
    float h = fc1b[j];
#pragma unroll 8
    for (int k = 0; k < D_EMB; ++k) h += hg[(size_t)g * D_EMB + k] * fc1W[k * 64 + j];
    h = lrelu(h) * fc2W[j];
#pragma unroll
    for (int m = 1; m < 64; m <<= 1) h += __shfl_xor(h, m);
    if (j == 0) out[g] = h + fc2b[0];
}

static inline size_t align256(size_t x) { return (x + 255) & ~(size_t)255; }

extern "C" void kernel_launch(void* const* d_in, const int* in_sizes, int n_in,
                              void* d_out, int out_size, void* d_ws, size_t ws_size,
                              hipStream_t stream) {
    const float* x     = (const float*)d_in[0];
    const int*   ei    = (const int*)d_in[1];
    const int*   batch = (const int*)d_in[2];
    const float* nfc_W = (const float*)d_in[3];
    const float* nfc_b = (const float*)d_in[4];
    const float* gn1_g = (const float*)d_in[5];
    const float* gn1_b = (const float*)d_in[6];
    const float* gc1_W = (const float*)d_in[7];
    const float* gc1_b = (const float*)d_in[8];
    const float* gn2_g = (const float*)d_in[9];
    const float* gn2_b = (const float*)d_in[10];
    const float* gc2_W = (const float*)d_in[11];
    const float* gc2_b = (const float*)d_in[12];
    const float* fc1_W = (const float*)d_in[13];
    const float* fc1_b = (const float*)d_in[14];
    const float* fc2_W = (const float*)d_in[15];
    const float* fc2_b = (const float*)d_in[16];

    char* ws = (char*)d_ws;
    size_t off = 0;
    // cnt + cursor + hg contiguous -> single memset
    int*   cnt    = (int*)(ws + off);   off += (size_t)NN * 4;
    int*   cursor = (int*)(ws + off);   off += (size_t)NN * 4;
    float* hg     = (float*)(ws + off); off += align256((size_t)GG * D_EMB * 4);
    float* dinv   = (float*)(ws + off); off += align256((size_t)NN * 4);
    int*   rowptr = (int*)(ws + off);   off += align256((size_t)(NN + 1) * 4);
    int*   bsum   = (int*)(ws + off);   off += align256((size_t)256 * 4);
    int*   esrc   = (int*)(ws + off);   off += align256((size_t)EE * 4);
    u16*   WtN    = (u16*)(ws + off);   off += align256((size_t)D_H * KP1 * 2);
    u16*   Wt1    = (u16*)(ws + off);   off += align256((size_t)D_H * D_H * 2);
    u16*   Wt2    = (u16*)(ws + off);   off += align256((size_t)D_EMB * D_H * 2);
    u16*   ha1b   = (u16*)(ws + off);   off += align256((size_t)NN * D_H * 2);
    u16*   y1b    = (u16*)(ws + off);   off += align256((size_t)NN * D_H * 2);
    u16*   ha2b   = (u16*)(ws + off);   off += align256((size_t)NN * D_H * 2);
    u16*   y2b    = (u16*)(ws + off);   off += align256((size_t)NN * D_EMB * 2);

    const int* src = ei;
    const int* dst = ei + EE;
    float* out_scores = (float*)d_out;
    float* out_ha     = (float*)d_out + GG;

    const int MB = (NN + 127) / 128;   // 391 GEMM tile blocks
    const int EB = (EE + 255) / 256;   // edge blocks riding inside fused dispatches
    const size_t zbytes = (size_t)NN * 8 + (size_t)GG * D_EMB * 4;  // cnt+cursor+hg

    // 1) one memset; weight casts (needed before GEMM-1)
    hipMemsetAsync(cnt, 0, zbytes, stream);
    cast_all<<<(WN_ELEMS + W1_ELEMS + W2_ELEMS + 255) / 256, 256, 0, stream>>>(
        nfc_W, gc1_W, gc2_W, WtN, Wt1, Wt2);

    // 2) ha1 = lrelu(x @ nfc_W + b)  [N,256] bf16 — with fused degree count
    gemm_f32a<<<MB + EB, 256, 0, stream>>>(x, WtN, nfc_b, ha1b, dst, cnt, MB);

    // 3) scan: wide scan1 then merged scan2+scan3
    scan1<<<NB_SCAN, 256, 0, stream>>>(cnt, rowptr, bsum, dinv, NN);
    scan23<<<NB_SCAN, 256, 0, stream>>>(rowptr, bsum);

    // 4) conv1 GEMM (3-buffer counted-vmcnt) — with fused CSR scatter; then agg+LN
    gemm_glds<D_H, true><<<MB + EB, 256, 0, stream>>>(
        ha1b, Wt1, dinv, y1b, src, dst, rowptr, cursor, esrc, MB);
    agg_ln<D_H, false, true, false><<<NN / 4, 256, 0, stream>>>(
        y1b, rowptr, esrc, dinv, gc1_b, gn1_g, gn1_b, ha2b, nullptr, nullptr, nullptr);

    // 5) conv2 GEMM (3-buffer counted-vmcnt); fused agg+LN+L2+pool -> out_ha + hg
    gemm_glds<D_EMB, false><<<MB, 256, 0, stream>>>(
        ha2b, Wt2, dinv, y2b, nullptr, nullptr, nullptr, nullptr, nullptr, MB);
    agg_ln<D_EMB, true, false, true><<<NN / 4, 256, 0, stream>>>(
        y2b, rowptr, esrc, dinv, gc2_b, gn2_g, gn2_b, nullptr, out_ha, batch, hg);

    // 6) tiny head
    head_kernel<<<GG, 64, 0, stream>>>(hg, fc1_W, fc1_b, fc2_W, fc2_b, out_scores);
}

// Round 11
// 246.289 us; speedup vs baseline: 1.0761x; 1.0184x over previous
//
#include <hip/hip_runtime.h>

#define NN 50000
#define EE 400000
#define GG 500
#define F_IN 92
#define KP1 96      // F_IN padded to multiple of 32
#define D_H 256
#define D_EMB 128
#define NB_SCAN 196 // ceil(NN/256)

typedef __attribute__((ext_vector_type(8))) short short8_t;
typedef __attribute__((ext_vector_type(4))) float floatx4;
typedef unsigned short u16;
typedef unsigned int u32;

__device__ __forceinline__ float lrelu(float v) { return v > 0.f ? v : 0.01f * v; }
__device__ __forceinline__ u16 f2b(float v) {
    union { float f; u32 u; } x; x.f = v;
    u32 r = x.u + 0x7FFFu + ((x.u >> 16) & 1u);   // RNE
    return (u16)(r >> 16);
}
__device__ __forceinline__ float wave_allsum(float v) {
#pragma unroll
    for (int m = 1; m < 64; m <<= 1) v += __shfl_xor(v, m);
    return v;
}
// direct global->LDS DMA, 16 B per lane; LDS dest = wave-uniform base + lane*16
__device__ __forceinline__ void glds16(const void* g, void* l) {
    __builtin_amdgcn_global_load_lds(
        (const __attribute__((address_space(1))) void*)g,
        (__attribute__((address_space(3))) void*)l, 16, 0, 0);
}

// ---------------- scan1: block-local exclusive prefix of cnt (+ fused dinv) ---------
__global__ void scan1(const int* __restrict__ cnt, int* __restrict__ excl,
                      int* __restrict__ bsum, float* __restrict__ dinv, int n) {
    __shared__ int sm[256];
    int i = blockIdx.x * 256 + threadIdx.x;
    int v = (i < n) ? cnt[i] : 0;
    if (i < n) dinv[i] = rsqrtf((float)v + 1.0f);   // +1 self loop
    sm[threadIdx.x] = v;
    __syncthreads();
#pragma unroll
    for (int off = 1; off < 256; off <<= 1) {
        int t = (threadIdx.x >= off) ? sm[threadIdx.x - off] : 0;
        __syncthreads();
        sm[threadIdx.x] += t;
        __syncthreads();
    }
    if (i < n) excl[i] = sm[threadIdx.x] - v;
    if (threadIdx.x == 255) bsum[blockIdx.x] = sm[255];
}

// --------- scan2+scan3 in ONE kernel: each block reduces its own bsum prefix ---------
__global__ void scan23(int* __restrict__ rowptr, const int* __restrict__ bsum) {
    __shared__ int sm[256];
    int b = blockIdx.x;
    int v = ((int)threadIdx.x < b) ? bsum[threadIdx.x] : 0;   // NB_SCAN-1 < 256
    sm[threadIdx.x] = v;
    __syncthreads();
#pragma unroll
    for (int off = 128; off > 0; off >>= 1) {
        if ((int)threadIdx.x < off) sm[threadIdx.x] += sm[threadIdx.x + off];
        __syncthreads();
    }
    int base = sm[0];
    int i = b * 256 + threadIdx.x;
    if (i < NN) rowptr[i] += base;
    if (i == 0) rowptr[NN] = EE;
}

// ---------------- all three weight transpose-casts in one kernel ----------------
#define WN_ELEMS (D_H * KP1)      // 24576
#define W1_ELEMS (D_H * D_H)      // 65536
#define W2_ELEMS (D_EMB * D_H)    // 32768
__global__ void cast_all(const float* __restrict__ nfc_W, const float* __restrict__ gc1_W,
                         const float* __restrict__ gc2_W, u16* __restrict__ WtN,
                         u16* __restrict__ Wt1, u16* __restrict__ Wt2) {
    int i = blockIdx.x * blockDim.x + threadIdx.x;
    if (i < WN_ELEMS) {
        int n = i / KP1, k = i % KP1;
        WtN[i] = f2b(k < F_IN ? nfc_W[(long)k * D_H + n] : 0.f);
    } else if (i < WN_ELEMS + W1_ELEMS) {
        int j = i - WN_ELEMS;
        int n = j / D_H, k = j % D_H;
        Wt1[j] = f2b(gc1_W[(long)k * D_H + n]);
    } else if (i < WN_ELEMS + W1_ELEMS + W2_ELEMS) {
        int j = i - WN_ELEMS - W1_ELEMS;
        int n = j / D_H, k = j % D_H;
        Wt2[j] = f2b(gc2_W[(long)k * D_EMB + n]);
    }
}

// ------------- GEMM-1 (+fused degree count): fp32 A, full-N 128x256 tile -------------
// K=96 is small: ALL staging (3 As sub-tiles + 12 B glds chunks) issued up front, then
// ONE vmcnt/lgkm drain + ONE barrier for the whole kernel, then 48 straight MFMAs.
// (r10 proved per-K-step vmcnt(0) drains are the stall; K=96 admits the degenerate
// fully-staged form.) Blocks >= MBLK run the edge-degree count.
__global__ __launch_bounds__(256) void gemm_f32a(const float* __restrict__ Af_,
                                                 const u16* __restrict__ Wt,
                                                 const float* __restrict__ bias,
                                                 u16* __restrict__ out,
                                                 const int* __restrict__ dstE,
                                                 int* __restrict__ cnt,
                                                 int MBLK) {
    if ((int)blockIdx.x >= MBLK) {   // -------- fused count path --------
        int e = (blockIdx.x - MBLK) * 256 + threadIdx.x;
        if (e < EE) atomicAdd(&cnt[dstE[e]], 1);
        return;
    }
    __shared__ u16 As[3][128][40];   // 30KB padded (uint4 thread writes)
    __shared__ u16 Bs[3][256][32];   // 48KB glds-staged, unpadded (lane*16B linear)
    int tid = threadIdx.x;
    int wave = tid >> 6, lane = tid & 63;
    int lm = lane & 15, lk = lane >> 4;
    int m0 = blockIdx.x * 128;
    int rowA = tid >> 1, skA = (tid & 1) * 16;
    int lr = lane >> 2, lc = (lane & 3) * 8;
    int gmA = m0 + rowA;
    const float* Af = Af_ + (size_t)gmA * F_IN;
    const u16* Bp[4];
#pragma unroll
    for (int ch = 0; ch < 4; ++ch)
        Bp[ch] = Wt + (size_t)(wave * 64 + ch * 16 + lr) * KP1 + lc;
    // ---- issue ALL A fp32 loads (latency overlaps B DMA below) ----
    float4 fv[3][4];
#pragma unroll
    for (int t = 0; t < 3; ++t) {
#pragma unroll
        for (int q = 0; q < 4; ++q) {
            int col = t * 32 + skA + 4 * q;
            fv[t][q] = make_float4(0.f, 0.f, 0.f, 0.f);
            if (gmA < NN && col < F_IN) fv[t][q] = *(const float4*)(Af + col); // F_IN%4==0
        }
    }
    // ---- issue ALL B global->LDS DMA (12 chunks) ----
#pragma unroll
    for (int t = 0; t < 3; ++t)
#pragma unroll
        for (int ch = 0; ch < 4; ++ch)
            glds16(Bp[ch] + t * 32, &Bs[t][wave * 64 + ch * 16][0]);
    // ---- pack + store all As (loads drain naturally per use) ----
#pragma unroll
    for (int t = 0; t < 3; ++t) {
        u32 pk[8];
#pragma unroll
        for (int t2 = 0; t2 < 8; ++t2) {
            float a = ((const float*)&fv[t][t2 >> 1])[(t2 & 1) * 2];
            float b = ((const float*)&fv[t][t2 >> 1])[(t2 & 1) * 2 + 1];
            pk[t2] = ((u32)f2b(b) << 16) | f2b(a);
        }
        *(uint4*)&As[t][rowA][skA] = make_uint4(pk[0], pk[1], pk[2], pk[3]);
        *(uint4*)&As[t][rowA][skA + 8] = make_uint4(pk[4], pk[5], pk[6], pk[7]);
    }
    __syncthreads();                   // single drain: all As stores + B DMA landed
    floatx4 acc[2][16] = {};
#pragma unroll
    for (int t = 0; t < 3; ++t) {
        short8_t af0 = *(const short8_t*)&As[t][wave * 32 + lm][lk * 8];
        short8_t af1 = *(const short8_t*)&As[t][wave * 32 + 16 + lm][lk * 8];
#pragma unroll
        for (int c = 0; c < 16; ++c) {
            short8_t bf = *(const short8_t*)&Bs[t][c * 16 + lm][lk * 8];
            acc[0][c] = __builtin_amdgcn_mfma_f32_16x16x32_bf16(af0, bf, acc[0][c], 0, 0, 0);
            acc[1][c] = __builtin_amdgcn_mfma_f32_16x16x32_bf16(af1, bf, acc[1][c], 0, 0, 0);
        }
    }
#pragma unroll
    for (int h = 0; h < 2; ++h) {
#pragma unroll
        for (int r = 0; r < 4; ++r) {
            int gm = m0 + wave * 32 + h * 16 + lk * 4 + r;
            if (gm >= NN) continue;
#pragma unroll
            for (int c = 0; c < 16; ++c) {
                int gn = c * 16 + lm;
                float v = acc[h][c][r] + bias[gn];
                out[(size_t)gm * D_H + gn] = f2b(lrelu(v));
            }
        }
    }
}

// ------- GEMM-2/3 (+optional fused CSR scatter): 3-buffer LDS, COUNTED vmcnt ---------
// T4 pattern: per K-step only stage(t) must be complete; stage(t+1)'s NLD loads stay in
// flight across the barrier -> s_waitcnt vmcnt(NLD), never 0 until the last step.
// Stage(t+2) is issued AFTER the barrier: a fast wave cannot rewrite buf[t%3] until it
// passes barrier t+1, which requires all waves done reading buf[t%3]. 3 bufs = safe.
// OOB tail rows read into the adjacent ws buffer (valid memory); never stored.
template <int ND, bool SCAT>
__global__ __launch_bounds__(256) void gemm_glds(const u16* __restrict__ A,
                                                 const u16* __restrict__ Wt,
                                                 const float* __restrict__ rscale,
                                                 u16* __restrict__ out,
                                                 const int* __restrict__ srcE,
                                                 const int* __restrict__ dstE,
                                                 const int* __restrict__ rowptr,
                                                 int* __restrict__ cursor,
                                                 int* __restrict__ esrc,
                                                 int MBLK) {
    if constexpr (SCAT) {
        if ((int)blockIdx.x >= MBLK) {   // -------- fused scatter path --------
            int e = (blockIdx.x - MBLK) * 256 + threadIdx.x;
            if (e < EE) {
                int d = dstE[e];
                int p = rowptr[d] + atomicAdd(&cursor[d], 1);
                esrc[p] = srcE[e];
            }
            return;
        }
    }
    constexpr int NC  = ND / 16;    // MFMA col-fragments (16 / 8)
    constexpr int BCH = ND / 64;    // B glds chunks per wave (4 / 2)
    constexpr int NLD = 2 + BCH;    // glds per wave per stage (6 / 4)
    __shared__ u16 As[3][128][32];  // 24KB
    __shared__ u16 Bs[3][ND][32];   // 48KB / 24KB  -> 72KB (2 blk/CU) / 48KB (3 blk/CU)
    int tid = threadIdx.x;
    int wave = tid >> 6, lane = tid & 63;
    int lm = lane & 15, lk = lane >> 4;
    int m0 = blockIdx.x * 128;
    int lr = lane >> 2;            // 0..15: row within a 16-row chunk
    int lc = (lane & 3) * 8;       // u16 col offset (16 B granules)
    const int Ka = D_H;
    const u16* ApA = A + (size_t)(m0 + wave * 32 + lr) * Ka + lc;
    const u16* ApB = A + (size_t)(m0 + wave * 32 + 16 + lr) * Ka + lc;
    const u16* Bp[BCH];
#pragma unroll
    for (int ch = 0; ch < BCH; ++ch)
        Bp[ch] = Wt + (size_t)(wave * (ND / 4) + ch * 16 + lr) * Ka + lc;

    auto stage = [&](int b, int k0) {
        glds16(ApA + k0, &As[b][wave * 32][0]);
        glds16(ApB + k0, &As[b][wave * 32 + 16][0]);
#pragma unroll
        for (int ch = 0; ch < BCH; ++ch)
            glds16(Bp[ch] + k0, &Bs[b][wave * (ND / 4) + ch * 16][0]);
    };

    floatx4 acc[2][NC] = {};
    constexpr int nk = D_H / 32;    // 8
    stage(0, 0);                     // prologue: 2 stages in flight
    stage(1, 32);
#pragma unroll
    for (int t = 0; t < nk; ++t) {
        // stage(t) must be complete; stage(t+1) (NLD loads) may remain outstanding
        if (t + 1 < nk) {
            asm volatile("s_waitcnt vmcnt(%0)" :: "n"(NLD) : "memory");
        } else {
            asm volatile("s_waitcnt vmcnt(0)" ::: "memory");
        }
        __builtin_amdgcn_s_barrier();
        __builtin_amdgcn_sched_barrier(0);
        if (t + 2 < nk) stage((t + 2) % 3, (t + 2) * 32);   // post-barrier: race-free
        int cur = t % 3;
        short8_t af0 = *(const short8_t*)&As[cur][wave * 32 + lm][lk * 8];
        short8_t af1 = *(const short8_t*)&As[cur][wave * 32 + 16 + lm][lk * 8];
#pragma unroll
        for (int c = 0; c < NC; ++c) {
            short8_t bf = *(const short8_t*)&Bs[cur][c * 16 + lm][lk * 8];
            acc[0][c] = __builtin_amdgcn_mfma_f32_16x16x32_bf16(af0, bf, acc[0][c], 0, 0, 0);
            acc[1][c] = __builtin_amdgcn_mfma_f32_16x16x32_bf16(af1, bf, acc[1][c], 0, 0, 0);
        }
        __builtin_amdgcn_sched_barrier(0);   // keep this step's ds_reads/MFMAs in place
    }
#pragma unroll
    for (int h = 0; h < 2; ++h) {
#pragma unroll
        for (int r = 0; r < 4; ++r) {
            int gm = m0 + wave * 32 + h * 16 + lk * 4 + r;
            if (gm >= NN) continue;
            float rs = rscale[gm];
#pragma unroll
            for (int c = 0; c < NC; ++c) {
                int gn = c * 16 + lm;
                out[(size_t)gm * ND + gn] = f2b(acc[h][c][r] * rs);
            }
        }
    }
}

// ------- fused CSR gather + self-loop + LayerNorm + lrelu (+L2) (+pool): wave/node ---
// Wave-uniform row addresses (SGPR base), 8 rows in flight. POOL: the 4 waves' final
// rows are staged in LDS and run-flushed by batch id -> hg atomics.
template <int U>
__device__ __forceinline__ void loadrow(const u32* __restrict__ p, u32* r) {
    if constexpr (U == 2) { uint2 t = *(const uint2*)p; r[0] = t.x; r[1] = t.y; }
    else                  { r[0] = *p; }
}
template <int D, bool L2N, bool TOBF, bool POOL>
__global__ __launch_bounds__(256) void agg_ln(const u16* __restrict__ y,
                                              const int* __restrict__ rowptr,
                                              const int* __restrict__ esrc,
                                              const float* __restrict__ dinv,
                                              const float* __restrict__ bias,
                                              const float* __restrict__ gamma,
                                              const float* __restrict__ beta,
                                              u16* __restrict__ outb,
                                              float* __restrict__ outf,
                                              const int* __restrict__ batch,
                                              float* __restrict__ hg) {
    constexpr int V = D / 64;    // elems per lane (4 / 2)
    constexpr int U = V / 2;     // dwords per lane (2 / 1)
    constexpr int RW = D / 2;    // dwords per row
    int wave = threadIdx.x >> 6, lane = threadIdx.x & 63;
    int i = blockIdx.x * 4 + wave;
    if constexpr (!POOL) { if (i >= NN) return; }
    int beg = __builtin_amdgcn_readfirstlane(rowptr[i]);
    int end = __builtin_amdgcn_readfirstlane(rowptr[i + 1]);
    const u32* yu = (const u32*)y;
    const int lu = lane * U;
    float accL[U] = {}, accH[U] = {};
    u32 r[8][U];
    int k = beg;
    for (; k + 7 < end; k += 8) {            // 8 rows in flight (mean degree = 8)
#pragma unroll
        for (int q = 0; q < 8; ++q) loadrow<U>(yu + (size_t)esrc[k + q] * RW + lu, r[q]);
#pragma unroll
        for (int j = 0; j < U; ++j) {
            float sL = 0.f, sH = 0.f;
#pragma unroll
            for (int q = 0; q < 8; ++q) {
                sL += __uint_as_float(r[q][j] << 16);
                sH += __uint_as_float(r[q][j] & 0xFFFF0000u);
            }
            accL[j] += sL; accH[j] += sH;
        }
    }
    for (; k + 3 < end; k += 4) {
#pragma unroll
        for (int q = 0; q < 4; ++q) loadrow<U>(yu + (size_t)esrc[k + q] * RW + lu, r[q]);
#pragma unroll
        for (int j = 0; j < U; ++j) {
            accL[j] += (__uint_as_float(r[0][j] << 16) + __uint_as_float(r[1][j] << 16))
                     + (__uint_as_float(r[2][j] << 16) + __uint_as_float(r[3][j] << 16));
            accH[j] += (__uint_as_float(r[0][j] & 0xFFFF0000u) + __uint_as_float(r[1][j] & 0xFFFF0000u))
                     + (__uint_as_float(r[2][j] & 0xFFFF0000u) + __uint_as_float(r[3][j] & 0xFFFF0000u));
        }
    }
    for (; k < end; ++k) {
        loadrow<U>(yu + (size_t)esrc[k] * RW + lu, r[0]);
#pragma unroll
        for (int j = 0; j < U; ++j) {
            accL[j] += __uint_as_float(r[0][j] << 16);
            accH[j] += __uint_as_float(r[0][j] & 0xFFFF0000u);
        }
    }
    // self loop
    loadrow<U>(yu + (size_t)i * RW + lu, r[0]);
#pragma unroll
    for (int j = 0; j < U; ++j) {
        accL[j] += __uint_as_float(r[0][j] << 16);
        accH[j] += __uint_as_float(r[0][j] & 0xFFFF0000u);
    }
    float di = dinv[i];
    float xv[V], lsum = 0.f;
#pragma unroll
    for (int j = 0; j < U; ++j) {
        xv[2 * j]     = accL[j] * di + bias[lane * V + 2 * j];
        xv[2 * j + 1] = accH[j] * di + bias[lane * V + 2 * j + 1];
    }
#pragma unroll
    for (int v = 0; v < V; ++v) lsum += xv[v];
    float mu = wave_allsum(lsum) * (1.0f / D);
    float l2 = 0.f;
#pragma unroll
    for (int v = 0; v < V; ++v) { xv[v] -= mu; l2 += xv[v] * xv[v]; }
    float rstd = rsqrtf(wave_allsum(l2) * (1.0f / D) + 1e-5f);
    float yv[V], ss = 0.f;
#pragma unroll
    for (int v = 0; v < V; ++v) {
        float t = xv[v] * rstd * gamma[lane * V + v] + beta[lane * V + v];
        t = lrelu(t);
        yv[v] = t; ss += t * t;
    }
    if constexpr (L2N) {
        float inv = 1.0f / fmaxf(sqrtf(wave_allsum(ss)), 1e-12f);
#pragma unroll
        for (int v = 0; v < V; ++v) yv[v] *= inv;
    }
    if constexpr (TOBF) {
        if constexpr (V == 4) {
            *(ushort4*)(outb + (size_t)i * D + lane * V) =
                make_ushort4(f2b(yv[0]), f2b(yv[1]), f2b(yv[2]), f2b(yv[3]));
        } else {
            *(ushort2*)(outb + (size_t)i * D + lane * V) = make_ushort2(f2b(yv[0]), f2b(yv[1]));
        }
    } else {
        if constexpr (V == 2) {
            *(float2*)(outf + (size_t)i * D + lane * V) = make_float2(yv[0], yv[1]);
        } else {
            *(float4*)(outf + (size_t)i * D + lane * V) = make_float4(yv[0], yv[1], yv[2], yv[3]);
        }
    }
    if constexpr (POOL) {   // D == D_EMB, V == 2: block-level run-flush pooling
        __shared__ float psm[4][D_EMB];
        __shared__ int pb[4];
        psm[wave][lane * 2]     = yv[0];
        psm[wave][lane * 2 + 1] = yv[1];
        if (lane == 0) pb[wave] = batch[i];
        __syncthreads();
        int tid = threadIdx.x;
        if (tid < D_EMB) {
            float acc = psm[0][tid];
            int cur = pb[0];
#pragma unroll
            for (int w = 1; w < 4; ++w) {
                if (pb[w] != cur) {
                    atomicAdd(&hg[(size_t)cur * D_EMB + tid], acc);
                    acc = 0.f; cur = pb[w];
                }
                acc += psm[w][tid];
            }
            atomicAdd(&hg[(size_t)cur * D_EMB + tid], acc);
        }
    }
}

// ---------- head MLP: one block (64 threads) per graph on pooled hg ----------
__global__ __launch_bounds__(64) void head_kernel(const float* __restrict__ hg,
                                                  const float* __restrict__ fc1W,
                                                  const float* __restrict__ fc1b,
                                                  const float* __restrict__ fc2W,
                                                  const float* __restrict__ fc2b,
                                                  float* __restrict__ out) {
    int g = blockIdx.x;
    int j = threadIdx.x;  // 0..63
    float h = fc1b[j];
#pragma unroll 8
    for (int k = 0; k < D_EMB; ++k) h += hg[(size_t)g * D_EMB + k] * fc1W[k * 64 + j];
    h = lrelu(h) * fc2W[j];
#pragma unroll
    for (int m = 1; m < 64; m <<= 1) h += __shfl_xor(h, m);
    if (j == 0) out[g] = h + fc2b[0];
}

static inline size_t align256(size_t x) { return (x + 255) & ~(size_t)255; }

extern "C" void kernel_launch(void* const* d_in, const int* in_sizes, int n_in,
                              void* d_out, int out_size, void* d_ws, size_t ws_size,
                              hipStream_t stream) {
    const float* x     = (const float*)d_in[0];
    const int*   ei    = (const int*)d_in[1];
    const int*   batch = (const int*)d_in[2];
    const float* nfc_W = (const float*)d_in[3];
    const float* nfc_b = (const float*)d_in[4];
    const float* gn1_g = (const float*)d_in[5];
    const float* gn1_b = (const float*)d_in[6];
    const float* gc1_W = (const float*)d_in[7];
    const float* gc1_b = (const float*)d_in[8];
    const float* gn2_g = (const float*)d_in[9];
    const float* gn2_b = (const float*)d_in[10];
    const float* gc2_W = (const float*)d_in[11];
    const float* gc2_b = (const float*)d_in[12];
    const float* fc1_W = (const float*)d_in[13];
    const float* fc1_b = (const float*)d_in[14];
    const float* fc2_W = (const float*)d_in[15];
    const float* fc2_b = (const float*)d_in[16];

    char* ws = (char*)d_ws;
    size_t off = 0;
    // cnt + cursor + hg contiguous -> single memset
    int*   cnt    = (int*)(ws + off);   off += (size_t)NN * 4;
    int*   cursor = (int*)(ws + off);   off += (size_t)NN * 4;
    float* hg     = (float*)(ws + off); off += align256((size_t)GG * D_EMB * 4);
    float* dinv   = (float*)(ws + off); off += align256((size_t)NN * 4);
    int*   rowptr = (int*)(ws + off);   off += align256((size_t)(NN + 1) * 4);
    int*   bsum   = (int*)(ws + off);   off += align256((size_t)256 * 4);
    int*   esrc   = (int*)(ws + off);   off += align256((size_t)EE * 4);
    u16*   WtN    = (u16*)(ws + off);   off += align256((size_t)D_H * KP1 * 2);
    u16*   Wt1    = (u16*)(ws + off);   off += align256((size_t)D_H * D_H * 2);
    u16*   Wt2    = (u16*)(ws + off);   off += align256((size_t)D_EMB * D_H * 2);
    u16*   ha1b   = (u16*)(ws + off);   off += align256((size_t)NN * D_H * 2);
    u16*   y1b    = (u16*)(ws + off);   off += align256((size_t)NN * D_H * 2);
    u16*   ha2b   = (u16*)(ws + off);   off += align256((size_t)NN * D_H * 2);
    u16*   y2b    = (u16*)(ws + off);   off += align256((size_t)NN * D_EMB * 2);

    const int* src = ei;
    const int* dst = ei + EE;
    float* out_scores = (float*)d_out;
    float* out_ha     = (float*)d_out + GG;

    const int MB = (NN + 127) / 128;   // 391 GEMM tile blocks
    const int EB = (EE + 255) / 256;   // edge blocks riding inside fused dispatches
    const size_t zbytes = (size_t)NN * 8 + (size_t)GG * D_EMB * 4;  // cnt+cursor+hg

    // 1) one memset; weight casts (needed before GEMM-1)
    hipMemsetAsync(cnt, 0, zbytes, stream);
    cast_all<<<(WN_ELEMS + W1_ELEMS + W2_ELEMS + 255) / 256, 256, 0, stream>>>(
        nfc_W, gc1_W, gc2_W, WtN, Wt1, Wt2);

    // 2) ha1 = lrelu(x @ nfc_W + b)  [N,256] bf16 — fully-staged single-barrier GEMM
    //    with fused degree count
    gemm_f32a<<<MB + EB, 256, 0, stream>>>(x, WtN, nfc_b, ha1b, dst, cnt, MB);

    // 3) scan: wide scan1 then merged scan2+scan3
    scan1<<<NB_SCAN, 256, 0, stream>>>(cnt, rowptr, bsum, dinv, NN);
    scan23<<<NB_SCAN, 256, 0, stream>>>(rowptr, bsum);

    // 4) conv1 GEMM (3-buffer counted-vmcnt) — with fused CSR scatter; then agg+LN
    gemm_glds<D_H, true><<<MB + EB, 256, 0, stream>>>(
        ha1b, Wt1, dinv, y1b, src, dst, rowptr, cursor, esrc, MB);
    agg_ln<D_H, false, true, false><<<NN / 4, 256, 0, stream>>>(
        y1b, rowptr, esrc, dinv, gc1_b, gn1_g, gn1_b, ha2b, nullptr, nullptr, nullptr);

    // 5) conv2 GEMM (3-buffer counted-vmcnt); fused agg+LN+L2+pool -> out_ha + hg
    gemm_glds<D_EMB, false><<<MB, 256, 0, stream>>>(
        ha2b, Wt2, dinv, y2b, nullptr, nullptr, nullptr, nullptr, nullptr, MB);
    agg_ln<D_EMB, true, false, true><<<NN / 4, 256, 0, stream>>>(
        y2b, rowptr, esrc, dinv, gc2_b, gn2_g, gn2_b, nullptr, out_ha, batch, hg);

    // 6) tiny head
    head_kernel<<<GG, 64, 0, stream>>>(hg, fc1_W, fc1_b, fc2_W, fc2_b, out_scores);
}